// Round 1
// baseline (175.850 us; speedup 1.0000x reference)
//
#include <hip/hip_runtime.h>
#include <math.h>

#define S_LEN   4032
#define HOURS   24
#define DAYS    168          // S_LEN / HOURS
#define DAY_PAD 28           // padded floats per day in LDS (16B-aligned, spreads banks)
#define NB_MAX  4096

// ---------------- block reduction helpers (256 threads = 4 waves) ----------------

__device__ inline float block_reduce_f(float v, float* scratch, int tid) {
#pragma unroll
    for (int o = 32; o > 0; o >>= 1) v += __shfl_down(v, o, 64);
    if ((tid & 63) == 0) scratch[tid >> 6] = v;
    __syncthreads();
    float r = 0.f;
    if (tid == 0) r = scratch[0] + scratch[1] + scratch[2] + scratch[3];
    __syncthreads();
    return r;   // valid on tid 0
}

__device__ inline double block_reduce_d(double v, double* scratch, int tid) {
#pragma unroll
    for (int o = 32; o > 0; o >>= 1) v += __shfl_down(v, o, 64);
    if ((tid & 63) == 0) scratch[tid >> 6] = v;
    __syncthreads();
    double r = 0.0;
    if (tid == 0) r = scratch[0] + scratch[1] + scratch[2] + scratch[3];
    __syncthreads();
    return r;   // valid on tid 0
}

// ---------------- kernel A: per-sample (one block per b) ----------------
// Outputs per b: A[b] = mean_d true_peak, P[b] = sum_d (pred_peak-true_peak)^2,
//                SEp[b] = sum step_w*sq_err, SWp[b] = sum step_w, Tp[b] = sum |dt|.

__global__ __launch_bounds__(256, 4) void day_kernel(
    const float* __restrict__ y_pred, const float* __restrict__ y_true,
    float* __restrict__ A, float* __restrict__ P,
    float* __restrict__ SEp, float* __restrict__ SWp, float* __restrict__ Tp)
{
    __shared__ float s_yt[DAYS * DAY_PAD];
    __shared__ float s_yp[DAYS * DAY_PAD];
    __shared__ float s_red[4];

    const int tid = threadIdx.x;
    const int b = blockIdx.x;
    const size_t base = (size_t)b * S_LEN;
    const float4* gp = (const float4*)(y_pred + base);
    const float4* gt = (const float4*)(y_true + base);

    // coalesced stage: 1008 float4 per row
    for (int i = tid; i < S_LEN / 4; i += 256) {
        float4 vp = gp[i];
        float4 vt = gt[i];
        int f = i * 4;
        int d = f / HOURS;          // 24 | f granularity: each float4 fully in one day
        int off = f - d * HOURS;
        *(float4*)&s_yp[d * DAY_PAD + off] = vp;
        *(float4*)&s_yt[d * DAY_PAD + off] = vt;
    }
    __syncthreads();

    float tpeak = 0.f, psq = 0.f, se = 0.f, sw = 0.f, terr = 0.f;
    if (tid < DAYS) {
        const float4* rt = (const float4*)&s_yt[tid * DAY_PAD];
        const float4* rp = (const float4*)&s_yp[tid * DAY_PAD];
        float yt[HOURS];
#pragma unroll
        for (int j = 0; j < 6; ++j) {
            float4 q = rt[j];
            yt[j * 4 + 0] = q.x; yt[j * 4 + 1] = q.y;
            yt[j * 4 + 2] = q.z; yt[j * 4 + 3] = q.w;
        }
        // true daytime argmax (strict > keeps FIRST max, matching jnp.argmax)
        float tbest = yt[6]; int tt = 6;
#pragma unroll
        for (int h = 7; h <= 20; ++h) {
            if (yt[h] > tbest) { tbest = yt[h]; tt = h; }
        }
        // fused pass over y_pred: pred argmax + weighted squared error
        float pbest = -1e30f; int pt = 6;
#pragma unroll
        for (int j = 0; j < 6; ++j) {
            float4 q = rp[j];
            float pv[4] = {q.x, q.y, q.z, q.w};
#pragma unroll
            for (int k = 0; k < 4; ++k) {
                int h = j * 4 + k;
                float v = pv[k];
                bool day = (h >= 6) && (h <= 20);
                if (day && v > pbest) { pbest = v; pt = h; }
                float bw = day ? 2.0f : 0.5f;
                float w = bw * (((h >= tt - 2) && (h <= tt + 2)) ? 3.0f : 1.0f);
                float dd = v - yt[h];
                se += dd * dd * w;
                sw += w;
            }
        }
        tpeak = tbest;
        float dp = pbest - tbest;
        psq = dp * dp;
        terr = fabsf((float)(pt - tt));
    }

    float rA = block_reduce_f(tpeak, s_red, tid);
    float rP = block_reduce_f(psq,   s_red, tid);
    float rE = block_reduce_f(se,    s_red, tid);
    float rW = block_reduce_f(sw,    s_red, tid);
    float rT = block_reduce_f(terr,  s_red, tid);
    if (tid == 0) {
        A[b]   = rA * (1.0f / (float)DAYS);
        P[b]   = rP;
        SEp[b] = rE;
        SWp[b] = rW;
        Tp[b]  = rT;
    }
}

// ---------------- kernel C: quantile (radix select) + final scalar ----------------

__global__ __launch_bounds__(256) void finalize_kernel(
    const float* __restrict__ A, const float* __restrict__ P,
    const float* __restrict__ SEp, const float* __restrict__ SWp,
    const float* __restrict__ Tp, float* __restrict__ out, int nB)
{
    __shared__ unsigned s_keys[NB_MAX];
    __shared__ unsigned s_hist[256];
    __shared__ unsigned s_wtot[4];
    __shared__ unsigned s_sel, s_srem;
    __shared__ double s_dred[4];

    const int tid = threadIdx.x;

    // load A as sortable uint keys (monotone float->uint transform)
    for (int i = tid; i < nB; i += 256) {
        unsigned u = __float_as_uint(A[i]);
        s_keys[i] = (u & 0x80000000u) ? ~u : (u | 0x80000000u);
    }
    __syncthreads();

    // quantile(0.75, linear): pos = q*(n-1)
    double pos = 0.75 * (double)(nB - 1);
    int lo = (int)pos;
    double frac = pos - (double)lo;
    int hi = (lo + 1 < nB) ? lo + 1 : lo;
    int ranks[2] = {lo, hi};
    float qv[2];

    for (int sidx = 0; sidx < 2; ++sidx) {
        int rem = ranks[sidx];
        unsigned prefix = 0;
        for (int shift = 24; shift >= 0; shift -= 8) {
            s_hist[tid] = 0;
            __syncthreads();
            unsigned maskAbove = (shift == 24) ? 0u : (0xFFFFFFFFu << (shift + 8));
            for (int i = tid; i < nB; i += 256) {
                unsigned k = s_keys[i];
                if ((k & maskAbove) == prefix)
                    atomicAdd(&s_hist[(k >> shift) & 0xFFu], 1u);
            }
            __syncthreads();
            // parallel 256-bin exclusive scan to locate the target bin
            unsigned c = s_hist[tid];
            unsigned x = c;
#pragma unroll
            for (int o = 1; o < 64; o <<= 1) {
                unsigned y = __shfl_up(x, o, 64);
                if ((tid & 63) >= o) x += y;
            }
            if ((tid & 63) == 63) s_wtot[tid >> 6] = x;
            __syncthreads();
            unsigned woff = 0;
            for (int w2 = 0; w2 < (tid >> 6); ++w2) woff += s_wtot[w2];
            unsigned incl = woff + x;
            unsigned excl = incl - c;
            if ((unsigned)rem >= excl && (unsigned)rem < incl) {
                s_sel = (unsigned)tid;
                s_srem = (unsigned)rem - excl;
            }
            __syncthreads();
            prefix |= (s_sel << shift);
            rem = (int)s_srem;
            __syncthreads();
        }
        unsigned bits = (prefix & 0x80000000u) ? (prefix & 0x7FFFFFFFu) : ~prefix;
        qv[sidx] = __uint_as_float(bits);
    }

    float thr = (float)((double)qv[0] + frac * ((double)qv[1] - (double)qv[0]));

    // final weighted sums in fp64
    double wp = 0.0, wsum = 0.0, se = 0.0, swt = 0.0, te = 0.0;
    for (int i = tid; i < nB; i += 256) {
        float a = A[i];
        float w = (a > thr) ? 1.5f : 1.0f;
        wp   += (double)w * (double)P[i];
        wsum += (double)w;
        se   += (double)SEp[i];
        swt  += (double)SWp[i];
        te   += (double)Tp[i];
    }
    wp   = block_reduce_d(wp,   s_dred, tid);
    wsum = block_reduce_d(wsum, s_dred, tid);
    se   = block_reduce_d(se,   s_dred, tid);
    swt  = block_reduce_d(swt,  s_dred, tid);
    te   = block_reduce_d(te,   s_dred, tid);

    if (tid == 0) {
        double L_overall = se / swt;
        double L_peak    = wp / ((double)DAYS * wsum);
        double L_timing  = 10.0 * te / ((double)nB * (double)DAYS);
        out[0] = (float)(L_overall + 2.0 * L_peak + L_timing);
    }
}

// ---------------- launcher ----------------

extern "C" void kernel_launch(void* const* d_in, const int* in_sizes, int n_in,
                              void* d_out, int out_size, void* d_ws, size_t ws_size,
                              hipStream_t stream) {
    const float* y_pred = (const float*)d_in[0];
    const float* y_true = (const float*)d_in[1];
    int total = in_sizes[0];
    int nB = total / S_LEN;          // 4096 for the reference shapes

    float* ws  = (float*)d_ws;
    float* A   = ws;
    float* P   = ws + 1 * NB_MAX;
    float* SEp = ws + 2 * NB_MAX;
    float* SWp = ws + 3 * NB_MAX;
    float* Tp  = ws + 4 * NB_MAX;

    day_kernel<<<nB, 256, 0, stream>>>(y_pred, y_true, A, P, SEp, SWp, Tp);
    finalize_kernel<<<1, 256, 0, stream>>>(A, P, SEp, SWp, Tp, (float*)d_out, nB);
}